// Round 6
// baseline (647.382 us; speedup 1.0000x reference)
//
#include <hip/hip_runtime.h>
#include <hip/hip_bf16.h>

// ---------------------------------------------------------------------------
// Fused 3-layer GRU (B*N=16384 seqs, T=20, HS=128) for MI355X / gfx950.
// One block = 64 sequences, 4 waves; wave w owns h-columns [w*32, w*32+32).
// Gate GEMMs via v_mfma_f32_16x16x32_f16; h state fp32 in regs (C/D layout),
// staged through LDS as f16 in A-operand layout each step.
// Weights pre-swizzled into B-fragment order (f16) in d_ws by prepack_kernel.
// ALL input/output dtypes are fp32 (follow the reference); dtype autodetect
// retained as a guard. Fragment layouts HW-verified by rounds 2-4 agreement.
// Round 5 was an infra failure (container died); this resubmits round 5's
// kernel unchanged to keep the experiment controlled.
// ---------------------------------------------------------------------------

typedef _Float16 half8 __attribute__((ext_vector_type(8)));
typedef float floatx4 __attribute__((ext_vector_type(4)));

#define MFMA16(a, b, c) __builtin_amdgcn_mfma_f32_16x16x32_f16((a), (b), (c), 0, 0, 0)

static __device__ __forceinline__ float ldin(const void* p, long i, bool f32) {
    return f32 ? ((const float*)p)[i]
               : __bfloat162float(((const __hip_bfloat16*)p)[i]);
}

// fp32 data read as bf16 gives mantissa-half elements with random exponents;
// genuine bf16 N(0,1) stays in (1e-8,1e8) or ==0.
static __device__ __forceinline__ bool detect_f32(const void* peT, const void* x) {
    const __hip_bfloat16* a = (const __hip_bfloat16*)peT;
    const __hip_bfloat16* b = (const __hip_bfloat16*)x;
    bool weird = false;
    for (int i = 0; i < 20; i++) {
        float v = fabsf(__bfloat162float(a[i]));
        if (!(v == 0.0f || (v > 1e-8f && v < 1e8f))) weird = true;
    }
    for (int i = 0; i < 64; i++) {
        float v = fabsf(__bfloat162float(b[i]));
        if (!(v == 0.0f || (v > 1e-8f && v < 1e8f))) weird = true;
    }
    return weird;
}

static __device__ __forceinline__ float fsigm(float x) {
    x = fminf(fmaxf(x, -60.f), 60.f);
    float e = __builtin_amdgcn_exp2f(-1.442695041f * x);
    return __builtin_amdgcn_rcpf(1.0f + e);
}
static __device__ __forceinline__ float ftanh(float x) {
    x = fminf(fmaxf(x, -30.f), 30.f);
    float e = __builtin_amdgcn_exp2f(2.885390082f * x);  // exp(2x)
    return 1.0f - 2.0f * __builtin_amdgcn_rcpf(1.0f + e);
}

// ws fragment layout (each frag = 512 halfs = 64 lanes x 8): slot order
//   [0,288)   Whh   (3 layers x 96)   frag id within layer: ((w*2+ct)*3+g)*4+ks
//   [288,480) WihR  (2 layers x 96)   same formula
//   [480,528) Wih0  (48)              ((w*2+ct)*3+g)*2+ks   (K=64)
//   [528,544) outW  (16)              w*4+ks
__global__ __launch_bounds__(64) void prepack_kernel(
    const void* __restrict__ Whh,
    const void* __restrict__ WihR,
    const void* __restrict__ Wih0,
    const void* __restrict__ outW,
    const void* __restrict__ peT,
    const void* __restrict__ x,
    _Float16* __restrict__ ws)
{
    const bool f32 = detect_f32(peT, x);
    int fid  = blockIdx.x;
    int lane = threadIdx.x;
    int nlo = lane & 15, quad = lane >> 4;
    const void* src;
    long base;
    int row, k0, ldk;
    if (fid < 288) {
        int l = fid / 96, r = fid % 96;
        int ks = r & 3, q1 = r >> 2, g = q1 % 3, q2 = q1 / 3, ct = q2 & 1, w = q2 >> 1;
        row = g * 128 + w * 32 + ct * 16 + nlo; k0 = ks * 32 + quad * 8; ldk = 128;
        src = Whh; base = (long)l * 384 * 128;
    } else if (fid < 480) {
        int f = fid - 288; int l = f / 96, r = f % 96;
        int ks = r & 3, q1 = r >> 2, g = q1 % 3, q2 = q1 / 3, ct = q2 & 1, w = q2 >> 1;
        row = g * 128 + w * 32 + ct * 16 + nlo; k0 = ks * 32 + quad * 8; ldk = 128;
        src = WihR; base = (long)l * 384 * 128;
    } else if (fid < 528) {
        int r = fid - 480;
        int ks = r & 1, q1 = r >> 1, g = q1 % 3, q2 = q1 / 3, ct = q2 & 1, w = q2 >> 1;
        row = g * 128 + w * 32 + ct * 16 + nlo; k0 = ks * 32 + quad * 8; ldk = 64;
        src = Wih0; base = 0;
    } else {
        int r = fid - 528; int ks = r & 3, w = r >> 2;
        row = w * 16 + nlo; k0 = ks * 32 + quad * 8; ldk = 128;
        src = outW; base = 0;
    }
    _Float16* d = ws + (long)fid * 512 + lane * 8;
#pragma unroll
    for (int j = 0; j < 8; j++)
        d[j] = (_Float16)ldin(src, base + (long)row * ldk + k0 + j, f32);
}

__global__ __launch_bounds__(256, 1) void rnn_fused(
    const void* __restrict__ x,
    const void* __restrict__ peA,
    const void* __restrict__ peT,
    const void* __restrict__ embW,
    const void* __restrict__ embB,
    const void* __restrict__ bih,
    const void* __restrict__ bhh,
    const void* __restrict__ outB,
    const _Float16* __restrict__ ws,
    float* __restrict__ out)            // <-- fp32 output (reference dtype)
{
    __shared__ __align__(16) _Float16 hA[3][64][136];
    __shared__ __align__(16) _Float16 eA[64][72];
    __shared__ float emb0[64], emb1[64], embb[64];

    const bool f32 = detect_f32(peT, x);

    const int tid  = threadIdx.x;
    const int w    = tid >> 6;
    const int lane = tid & 63;
    const int nlo  = lane & 15;
    const int quad = lane >> 4;
    const int qk   = quad * 8;
    const int m0   = blockIdx.x * 64;

    {
        _Float16* hz = &hA[0][0][0];
        for (int i = tid; i < 3 * 64 * 136; i += 256) hz[i] = (_Float16)0.f;
    }
    if (tid < 64) {
        emb0[tid] = ldin(embW, tid * 2 + 0, f32);
        emb1[tid] = ldin(embW, tid * 2 + 1, f32);
        embb[tid] = ldin(embB, tid, f32);
    }

    float biasR[3][2], biasZ[3][2], biasNi[3][2], biasNh[3][2];
#pragma unroll
    for (int l = 0; l < 3; l++)
#pragma unroll
        for (int ct = 0; ct < 2; ct++) {
            int c = w * 32 + ct * 16 + nlo;
            biasR[l][ct]  = ldin(bih, l * 384 + c, f32) + ldin(bhh, l * 384 + c, f32);
            biasZ[l][ct]  = ldin(bih, l * 384 + 128 + c, f32) + ldin(bhh, l * 384 + 128 + c, f32);
            biasNi[l][ct] = ldin(bih, l * 384 + 256 + c, f32);
            biasNh[l][ct] = ldin(bhh, l * 384 + 256 + c, f32);
        }

    float hold[3][4][2][4];
#pragma unroll
    for (int l = 0; l < 3; l++)
#pragma unroll
        for (int rt = 0; rt < 4; rt++)
#pragma unroll
            for (int ct = 0; ct < 2; ct++)
#pragma unroll
                for (int rg = 0; rg < 4; rg++) hold[l][rt][ct][rg] = 0.f;

    const int em = tid >> 2;
    const int ej = (tid & 3) * 16;
    const float peAg = ldin(peA, (m0 + em) & 7, f32);

    half8 zf;
#pragma unroll
    for (int j = 0; j < 8; j++) zf[j] = (_Float16)0.f;

    __syncthreads();

    for (int t = 0; t < 20; t++) {
        {
            float x0 = ldin(x, ((long)(m0 + em) * 20 + t) * 2 + 0, f32);
            float x1 = ldin(x, ((long)(m0 + em) * 20 + t) * 2 + 1, f32);
            float pe = ldin(peT, t, f32) + peAg;
            float xp0 = x0 + pe, xp1 = x1 + pe;
#pragma unroll
            for (int jj = 0; jj < 16; jj++) {
                float e = fmaf(emb0[ej + jj], xp0, fmaf(emb1[ej + jj], xp1, embb[ej + jj]));
                eA[em][ej + jj] = (_Float16)fmaxf(e, 0.f);
            }
        }
        __syncthreads();

#pragma unroll
        for (int l = 0; l < 3; l++) {
            const int KGI = (l == 0) ? 2 : 4;

            half8 Agh[4][4];
#pragma unroll
            for (int rt = 0; rt < 4; rt++)
#pragma unroll
                for (int ks = 0; ks < 4; ks++)
                    Agh[rt][ks] = *(const half8*)&hA[l][rt * 16 + nlo][ks * 32 + qk];
            half8 Agi[4][4];
#pragma unroll
            for (int rt = 0; rt < 4; rt++)
#pragma unroll
                for (int ks = 0; ks < 4; ks++) {
                    Agi[rt][ks] = zf;
                    if (ks < KGI)
                        Agi[rt][ks] = (l == 0)
                            ? *(const half8*)&eA[rt * 16 + nlo][ks * 32 + qk]
                            : *(const half8*)&hA[l - 1][rt * 16 + nlo][ks * 32 + qk];
                }

#pragma unroll
            for (int ct = 0; ct < 2; ct++) {
                half8 Bgh[3][4], Bgi[3][4];
#pragma unroll
                for (int g = 0; g < 3; g++)
#pragma unroll
                    for (int ks = 0; ks < 4; ks++)
                        Bgh[g][ks] = *(const half8*)(ws +
                            ((long)(l * 96 + (((w * 2 + ct) * 3 + g) * 4 + ks))) * 512 + lane * 8);
#pragma unroll
                for (int g = 0; g < 3; g++)
#pragma unroll
                    for (int ks = 0; ks < 4; ks++) {
                        Bgi[g][ks] = zf;
                        if (ks < KGI)
                            Bgi[g][ks] = (l == 0)
                                ? *(const half8*)(ws +
                                      ((long)(480 + (((w * 2 + ct) * 3 + g) * 2 + ks))) * 512 + lane * 8)
                                : *(const half8*)(ws +
                                      ((long)(288 + (l - 1) * 96 + (((w * 2 + ct) * 3 + g) * 4 + ks))) * 512 + lane * 8);
                    }

#pragma unroll
                for (int rt = 0; rt < 4; rt++) {
                    float bR = biasR[l][ct], bZ = biasZ[l][ct];
                    float bNi = biasNi[l][ct], bNh = biasNh[l][ct];
                    floatx4 aR  = {bR, bR, bR, bR};
                    floatx4 aZ  = {bZ, bZ, bZ, bZ};
                    floatx4 aNi = {bNi, bNi, bNi, bNi};
                    floatx4 aNh = {bNh, bNh, bNh, bNh};
#pragma unroll
                    for (int ks = 0; ks < 4; ks++) {
                        aR  = MFMA16(Agh[rt][ks], Bgh[0][ks], aR);
                        aZ  = MFMA16(Agh[rt][ks], Bgh[1][ks], aZ);
                        aNh = MFMA16(Agh[rt][ks], Bgh[2][ks], aNh);
                    }
#pragma unroll
                    for (int ks = 0; ks < 4; ks++) {
                        if (ks < KGI) {
                            aR  = MFMA16(Agi[rt][ks], Bgi[0][ks], aR);
                            aZ  = MFMA16(Agi[rt][ks], Bgi[1][ks], aZ);
                            aNi = MFMA16(Agi[rt][ks], Bgi[2][ks], aNi);
                        }
                    }
#pragma unroll
                    for (int rg = 0; rg < 4; rg++) {
                        float r = fsigm(aR[rg]);
                        float z = fsigm(aZ[rg]);
                        float n = ftanh(aNi[rg] + r * aNh[rg]);
                        float h = hold[l][rt][ct][rg];
                        hold[l][rt][ct][rg] = n + z * (h - n);
                    }
                }
            }
            __syncthreads();
#pragma unroll
            for (int rt = 0; rt < 4; rt++)
#pragma unroll
                for (int ct = 0; ct < 2; ct++) {
                    int row = rt * 16 + quad * 4;
                    int col = w * 32 + ct * 16 + nlo;
#pragma unroll
                    for (int rg = 0; rg < 4; rg++)
                        hA[l][row + rg][col] = (_Float16)hold[l][rt][ct][rg];
                }
            __syncthreads();
        }
    }

    // ---- epilogue 1: out = h3(T) @ outW^T + out_b  (fp32) ----
    {
        half8 Bo[4];
#pragma unroll
        for (int ks = 0; ks < 4; ks++)
            Bo[ks] = *(const half8*)(ws + ((long)(528 + w * 4 + ks)) * 512 + lane * 8);
        float ob = ldin(outB, w * 16 + nlo, f32);
#pragma unroll
        for (int rt = 0; rt < 4; rt++) {
            floatx4 acc = {ob, ob, ob, ob};
#pragma unroll
            for (int ks = 0; ks < 4; ks++) {
                half8 a = *(const half8*)&hA[2][rt * 16 + nlo][ks * 32 + qk];
                acc = MFMA16(a, Bo[ks], acc);
            }
#pragma unroll
            for (int rg = 0; rg < 4; rg++)
                out[(long)(m0 + rt * 16 + quad * 4 + rg) * 64 + w * 16 + nlo] = acc[rg];
        }
    }

    // ---- epilogue 2: hidden finals (fp32), rows with (global m) % 8 == 7 ----
    if (quad & 1) {
#pragma unroll
        for (int l = 0; l < 3; l++)
#pragma unroll
            for (int rt = 0; rt < 4; rt++)
#pragma unroll
                for (int ct = 0; ct < 2; ct++) {
                    int m = m0 + rt * 16 + quad * 4 + 3;
                    long idx = 1048576L + ((long)l * 2048 + (m >> 3)) * 128 +
                               (w * 32 + ct * 16 + nlo);
                    out[idx] = hold[l][rt][ct][3];
                }
    }
}

extern "C" void kernel_launch(void* const* d_in, const int* in_sizes, int n_in,
                              void* d_out, int out_size, void* d_ws, size_t ws_size,
                              hipStream_t stream)
{
    int ix = 0, ipeA = 1, ipeT = 2, iembW = 3, iembB = 4, iWih0 = 5, iWihR = 6,
        iWhh = 7, ibih = 8, ibhh = 9, ioutW = 10, ioutB = 11;
    int f64 = -1, s64 = -1, f1152 = -1, s1152 = -1;
    for (int i = 0; i < n_in; i++) {
        int s = in_sizes[i];
        if      (s == 655360) ix = i;
        else if (s == 8)      ipeA = i;
        else if (s == 20)     ipeT = i;
        else if (s == 128)    iembW = i;
        else if (s == 24576)  iWih0 = i;
        else if (s == 98304)  iWihR = i;
        else if (s == 147456) iWhh = i;
        else if (s == 8192)   ioutW = i;
        else if (s == 64)     { if (f64 < 0) f64 = i; else s64 = i; }
        else if (s == 1152)   { if (f1152 < 0) f1152 = i; else s1152 = i; }
    }
    if (f64 >= 0)   { iembB = f64;  ioutB = (s64  >= 0 ? s64  : f64); }
    if (f1152 >= 0) { ibih = f1152; ibhh = (s1152 >= 0 ? s1152 : f1152); }

    _Float16* ws = (_Float16*)d_ws;           // 544 frags * 1KB = 557056 B
    float* out = (float*)d_out;

    hipLaunchKernelGGL(prepack_kernel, dim3(544), dim3(64), 0, stream,
                       d_in[iWhh], d_in[iWihR], d_in[iWih0], d_in[ioutW],
                       d_in[ipeT], d_in[ix], ws);
    hipLaunchKernelGGL(rnn_fused, dim3(256), dim3(256), 0, stream,
                       d_in[ix], d_in[ipeA], d_in[ipeT], d_in[iembW], d_in[iembB],
                       d_in[ibih], d_in[ibhh], d_in[ioutB], ws, out);
}